// Round 6
// baseline (159.666 us; speedup 1.0000x reference)
//
#include <hip/hip_runtime.h>
#include <hip/hip_bf16.h>
#include <stdint.h>

#define DI __device__ __forceinline__

typedef __bf16 bf16x8 __attribute__((ext_vector_type(8)));
typedef float f32x4 __attribute__((ext_vector_type(4)));
typedef unsigned short ushortx8 __attribute__((ext_vector_type(8)));

// fp32 -> bf16 round-to-nearest-even (scalar path)
DI unsigned short f2bf(float f) {
    unsigned int u = __builtin_bit_cast(unsigned int, f);
    u += 0x7fffu + ((u >> 16) & 1u);
    return (unsigned short)(u >> 16);
}

// packed fp32x2 -> bf16x2 (1 VALU op). lo -> bits 0-15, hi -> bits 16-31.
DI unsigned int cvt_pk_bf16(float lo, float hi) {
    unsigned int r;
    asm("v_cvt_pk_bf16_f32 %0, %1, %2" : "=v"(r) : "v"(lo), "v"(hi));
    return r;
}

DI f32x4 mfma_16x16x32_bf16(bf16x8 a, bf16x8 b, f32x4 c) {
    return __builtin_amdgcn_mfma_f32_16x16x32_bf16(a, b, c, 0, 0, 0);
}

// async global->LDS, 16B per lane. LDS dest: wave-uniform base + lane*16.
DI void gload16(const unsigned short* g, unsigned short* l) {
    __builtin_amdgcn_global_load_lds(
        (const __attribute__((address_space(1))) void*)g,
        (__attribute__((address_space(3))) void*)l, 16, 0, 0);
}

// ---------------------------------------------------------------------------
// k_cvt: fp32 -> bf16 elementwise for Q, K, V (grid.y selects tensor).
// ---------------------------------------------------------------------------
__global__ __launch_bounds__(256) void k_cvt(
    const float* __restrict__ s0, const float* __restrict__ s1, const float* __restrict__ s2,
    unsigned short* __restrict__ d0, unsigned short* __restrict__ d1, unsigned short* __restrict__ d2)
{
    const int z = blockIdx.y;
    const float* s = z == 0 ? s0 : z == 1 ? s1 : s2;
    unsigned short* d = z == 0 ? d0 : z == 1 ? d1 : d2;
    const int i0 = blockIdx.x * 256 + threadIdx.x;
    #pragma unroll
    for (int it = 0; it < 4; ++it) {
        const int i = i0 + it * 262144;
        const float4 v = reinterpret_cast<const float4*>(s)[i];
        uint2 pk;
        pk.x = cvt_pk_bf16(v.x, v.y);
        pk.y = cvt_pk_bf16(v.z, v.w);
        reinterpret_cast<uint2*>(d)[i] = pk;
    }
}

// ---------------------------------------------------------------------------
// k_wt: W fp32 [1024][1024] -> Wt bf16 [n][k] (transposed), grid.z = 4 matrices.
// ---------------------------------------------------------------------------
__global__ __launch_bounds__(256) void k_wt(
    const float* __restrict__ w0, const float* __restrict__ w1,
    const float* __restrict__ w2, const float* __restrict__ w3,
    unsigned short* __restrict__ o0, unsigned short* __restrict__ o1,
    unsigned short* __restrict__ o2, unsigned short* __restrict__ o3)
{
    constexpr int N = 1024;
    const int z = blockIdx.z;
    const float* W = z == 0 ? w0 : z == 1 ? w1 : z == 2 ? w2 : w3;
    unsigned short* O = z == 0 ? o0 : z == 1 ? o1 : z == 2 ? o2 : o3;

    __shared__ unsigned short L[64 * 64];
    const int tid = threadIdx.x;
    const int k0 = blockIdx.x * 64, n0 = blockIdx.y * 64;

    const int r = tid >> 2, cbase = (tid & 3) * 16;
    #pragma unroll
    for (int i = 0; i < 4; ++i) {
        const int c = cbase + i * 4;
        const float4 v = *reinterpret_cast<const float4*>(&W[(size_t)(k0 + r) * N + n0 + c]);
        uint2 pk;
        pk.x = cvt_pk_bf16(v.x, v.y);
        pk.y = cvt_pk_bf16(v.z, v.w);
        const int byte = r * 128 + ((c * 2) ^ ((r & 7) << 4));
        *reinterpret_cast<uint2*>(reinterpret_cast<char*>(L) + byte) = pk;
    }
    __syncthreads();

    const int n = tid >> 2, kc = (tid & 3) * 16;
    ushortx8 v0, v1;
    #pragma unroll
    for (int j = 0; j < 8; ++j) {
        const int ka = kc + j, kb2 = kc + 8 + j;
        v0[j] = *reinterpret_cast<const unsigned short*>(
            reinterpret_cast<const char*>(L) + ka * 128 + ((n * 2) ^ ((ka & 7) << 4)));
        v1[j] = *reinterpret_cast<const unsigned short*>(
            reinterpret_cast<const char*>(L) + kb2 * 128 + ((n * 2) ^ ((kb2 & 7) << 4)));
    }
    unsigned short* op = &O[(size_t)(n0 + n) * N + k0 + kc];
    *reinterpret_cast<ushortx8*>(op) = v0;
    *reinterpret_cast<ushortx8*>(op + 8) = v1;
}

// ---------------------------------------------------------------------------
// m97-style bf16 GEMM (unchanged from round 5).
// ---------------------------------------------------------------------------
template <int MODE>
__global__ __launch_bounds__(256) void k_gemm_bf16(
    const unsigned short* __restrict__ A0, const unsigned short* __restrict__ A1,
    const unsigned short* __restrict__ A2,
    const unsigned short* __restrict__ B0, const unsigned short* __restrict__ B1,
    const unsigned short* __restrict__ B2,
    const float* __restrict__ bias0, const float* __restrict__ bias1,
    const float* __restrict__ bias2,
    void* C0, void* C1, void* C2)
{
    constexpr int K = 1024, N = 1024;
    const int z = MODE ? blockIdx.z : 0;
    const unsigned short* A  = z == 0 ? A0 : z == 1 ? A1 : A2;
    const unsigned short* Bt = z == 0 ? B0 : z == 1 ? B1 : B2;
    const float* bias        = z == 0 ? bias0 : z == 1 ? bias1 : bias2;
    void* C                  = z == 0 ? C0 : z == 1 ? C1 : C2;

    __shared__ unsigned short As[128 * 32];
    __shared__ unsigned short Bs[128 * 32];

    const int tid  = threadIdx.x;
    const int lane = tid & 63;
    const int w    = tid >> 6;
    const int wr   = w >> 1, wc = w & 1;
    const int fr   = lane & 15, kg = lane >> 4;
    const int m0   = blockIdx.x * 128, n0 = blockIdx.y * 128;

    const int srow = lane >> 2;
    const int sk8  = (lane & 3) * 8;

    f32x4 acc[4][4] = {};

    for (int t = 0; t < K / 32; ++t) {
        const int k0 = t * 32;
        #pragma unroll
        for (int i = 0; i < 2; ++i) {
            const int c = w * 2 + i;
            const int row = c * 16 + srow;
            gload16(&A[(size_t)(m0 + row) * K + k0 + sk8], &As[c * 512]);
            gload16(&Bt[(size_t)(n0 + row) * K + k0 + sk8], &Bs[c * 512]);
        }
        __syncthreads();

        bf16x8 af[4], bfj[4];
        #pragma unroll
        for (int i = 0; i < 4; ++i)
            af[i] = *reinterpret_cast<const bf16x8*>(&As[(wr * 64 + i * 16 + fr) * 32 + kg * 8]);
        #pragma unroll
        for (int j = 0; j < 4; ++j)
            bfj[j] = *reinterpret_cast<const bf16x8*>(&Bs[(wc * 64 + j * 16 + fr) * 32 + kg * 8]);
        #pragma unroll
        for (int i = 0; i < 4; ++i)
            #pragma unroll
            for (int j = 0; j < 4; ++j)
                acc[i][j] = mfma_16x16x32_bf16(af[i], bfj[j], acc[i][j]);
        __syncthreads();
    }

    if (MODE == 1 && z == 2) {
        unsigned short* vt = reinterpret_cast<unsigned short*>(C);
        #pragma unroll
        for (int i = 0; i < 4; ++i) {
            const int m = m0 + wr * 64 + i * 16 + kg * 4;
            const int bb = m >> 11, s = m & 2047;
            #pragma unroll
            for (int j = 0; j < 4; ++j) {
                const int n = n0 + wc * 64 + j * 16 + fr;
                const float bv = bias[n];
                uint2 pk;
                pk.x = cvt_pk_bf16(acc[i][j][0] + bv, acc[i][j][1] + bv);
                pk.y = cvt_pk_bf16(acc[i][j][2] + bv, acc[i][j][3] + bv);
                *reinterpret_cast<uint2*>(&vt[((size_t)(bb * 1024 + n)) * 2048 + s]) = pk;
            }
        }
    } else if (MODE == 1) {
        const float sc = (z == 0) ? 0.125f : 1.0f;
        unsigned short* Cb = reinterpret_cast<unsigned short*>(C);
        #pragma unroll
        for (int i = 0; i < 4; ++i) {
            const int m = m0 + wr * 64 + i * 16 + kg * 4;
            #pragma unroll
            for (int j = 0; j < 4; ++j) {
                const int n = n0 + wc * 64 + j * 16 + fr;
                const float bv = bias[n];
                const unsigned int p0 = cvt_pk_bf16((acc[i][j][0] + bv) * sc, (acc[i][j][1] + bv) * sc);
                const unsigned int p1 = cvt_pk_bf16((acc[i][j][2] + bv) * sc, (acc[i][j][3] + bv) * sc);
                Cb[(size_t)(m + 0) * N + n] = (unsigned short)p0;
                Cb[(size_t)(m + 1) * N + n] = (unsigned short)(p0 >> 16);
                Cb[(size_t)(m + 2) * N + n] = (unsigned short)p1;
                Cb[(size_t)(m + 3) * N + n] = (unsigned short)(p1 >> 16);
            }
        }
    } else {
        float* Cf = reinterpret_cast<float*>(C);
        #pragma unroll
        for (int i = 0; i < 4; ++i) {
            const int m = m0 + wr * 64 + i * 16 + kg * 4;
            #pragma unroll
            for (int j = 0; j < 4; ++j) {
                const int n = n0 + wc * 64 + j * 16 + fr;
                const float bv = bias[n];
                #pragma unroll
                for (int r = 0; r < 4; ++r)
                    Cf[(size_t)(m + r) * N + n] = acc[i][j][r] + bv;
            }
        }
    }
}

// ---------------------------------------------------------------------------
// V tail suffix sums (unchanged).
// ---------------------------------------------------------------------------
__global__ __launch_bounds__(256) void k_vtail(
    const unsigned short* __restrict__ vt, float* __restrict__ vtail)
{
    const int row = blockIdx.x * 4 + (threadIdx.x >> 6);
    const int l = threadIdx.x & 63;
    const unsigned short* p = &vt[(size_t)row * 2048 + l * 32];
    float s = 0.f;
    #pragma unroll
    for (int i = 0; i < 4; ++i) {
        ushortx8 v = *reinterpret_cast<const ushortx8*>(&p[i * 8]);
        #pragma unroll
        for (int e = 0; e < 8; ++e)
            s += __builtin_bit_cast(float, (unsigned int)v[e] << 16);
    }
    #pragma unroll
    for (int off = 1; off < 64; off <<= 1) {
        const float t = __shfl_down(s, off, 64);
        s += (l + off < 64) ? t : 0.f;
    }
    float tv = __shfl(s, (2 * l + 2) & 63, 64);
    if (l == 31) tv = 0.f;
    if (l < 32) vtail[(size_t)row * 32 + l] = tv;
}

// ---------------------------------------------------------------------------
// Attention v4: QBLK=128 (4 waves x 32 q-rows), T14 register prefetch of the
// next K/V tile, biggest-first qt remap. Swapped QK^T + V-tail as before.
// DT: -1 = unmasked tile; 0/1 = diagonal tile index within the 128-row block.
// ---------------------------------------------------------------------------
template <int DT>
DI void attn_tile2(const unsigned short (*Ks)[72], const unsigned short (*Vts)[72],
                   unsigned short (*Pw)[72],
                   bf16x8 qA0, bf16x8 qA1, bf16x8 qB0, bf16x8 qB1,
                   f32x4 (&oA)[4], f32x4 (&oB)[4], float& lsA, float& lsB,
                   int w, int fr, int kg)
{
    #pragma unroll
    for (int j = 0; j < 4; ++j) {
        const bf16x8 kf0 = *reinterpret_cast<const bf16x8*>(&Ks[j * 16 + fr][kg * 8]);
        const bf16x8 kf1 = *reinterpret_cast<const bf16x8*>(&Ks[j * 16 + fr][32 + kg * 8]);
        f32x4 sA = {0.f, 0.f, 0.f, 0.f}, sB = {0.f, 0.f, 0.f, 0.f};
        sA = mfma_16x16x32_bf16(kf0, qA0, sA);
        sA = mfma_16x16x32_bf16(kf1, qA1, sA);
        sB = mfma_16x16x32_bf16(kf0, qB0, sB);
        sB = mfma_16x16x32_bf16(kf1, qB1, sB);
        float pA[4], pB[4];
        #pragma unroll
        for (int r = 0; r < 4; ++r) {
            float eA = __expf(sA[r]);
            float eB = __expf(sB[r]);
            if (DT >= 0) {
                const int key = DT * 64 + j * 16 + kg * 4 + r;   // within 128-row block
                if (key > w * 32 + fr)      eA = 1.0f;            // exp(-1e-8)==1.0f
                if (key > w * 32 + 16 + fr) eB = 1.0f;
            }
            pA[r] = eA; lsA += eA;
            pB[r] = eB; lsB += eB;
        }
        uint2 wa, wb;
        wa.x = cvt_pk_bf16(pA[0], pA[1]); wa.y = cvt_pk_bf16(pA[2], pA[3]);
        wb.x = cvt_pk_bf16(pB[0], pB[1]); wb.y = cvt_pk_bf16(pB[2], pB[3]);
        *reinterpret_cast<uint2*>(&Pw[fr][j * 16 + kg * 4]) = wa;
        *reinterpret_cast<uint2*>(&Pw[16 + fr][j * 16 + kg * 4]) = wb;
    }
    #pragma unroll
    for (int kk = 0; kk < 2; ++kk) {
        const bf16x8 pfA = *reinterpret_cast<const bf16x8*>(&Pw[fr][kk * 32 + kg * 8]);
        const bf16x8 pfB = *reinterpret_cast<const bf16x8*>(&Pw[16 + fr][kk * 32 + kg * 8]);
        #pragma unroll
        for (int n = 0; n < 4; ++n) {
            const bf16x8 vf = *reinterpret_cast<const bf16x8*>(&Vts[n * 16 + fr][kk * 32 + kg * 8]);
            oA[n] = mfma_16x16x32_bf16(pfA, vf, oA[n]);
            oB[n] = mfma_16x16x32_bf16(pfB, vf, oB[n]);
        }
    }
}

__global__ __launch_bounds__(256) void k_attn(
    const unsigned short* __restrict__ qp,
    const unsigned short* __restrict__ kp,
    const unsigned short* __restrict__ vt,
    const float* __restrict__ vtail,
    unsigned short* __restrict__ ctx)
{
    constexpr int S = 2048, D = 1024;
    const int qt = (S / 128 - 1) - blockIdx.x;   // biggest-first dispatch
    const int h  = blockIdx.y;
    const int b  = blockIdx.z;

    __shared__ unsigned short Ks[64][72];
    __shared__ unsigned short Vts[64][72];
    __shared__ unsigned short Pls[4][32][72];

    const int tid  = threadIdx.x;
    const int lane = tid & 63, w = tid >> 6;
    const int fr   = lane & 15, kg = lane >> 4;

    const size_t baseQ = ((size_t)b * S) * D + (size_t)h * 64;
    const size_t baseV = ((size_t)b * D + (size_t)h * 64) * S;
    const int qw0 = qt * 128 + w * 32;           // wave's first q row

    bf16x8 qA0, qA1, qB0, qB1;
    {
        const size_t ra = baseQ + (size_t)(qw0 + fr) * D;
        qA0 = *reinterpret_cast<const bf16x8*>(&qp[ra + kg * 8]);
        qA1 = *reinterpret_cast<const bf16x8*>(&qp[ra + 32 + kg * 8]);
        const size_t rb = ra + (size_t)16 * D;
        qB0 = *reinterpret_cast<const bf16x8*>(&qp[rb + kg * 8]);
        qB1 = *reinterpret_cast<const bf16x8*>(&qp[rb + 32 + kg * 8]);
    }

    f32x4 oA[4] = {}, oB[4] = {};
    float lsA = 0.f, lsB = 0.f;

    const int sr  = tid >> 3;        // staging row 0..31
    const int sc8 = (tid & 7) * 8;   // staging col (8 bf16)
    const int NT  = 2 * qt + 2;      // tiles to sweep (last 2 are diagonal)

    // prologue: load tile 0 into registers
    ushortx8 kr0, kr1, vr0, vr1;
    {
        kr0 = *reinterpret_cast<const ushortx8*>(&kp[baseQ + (size_t)(sr) * D + sc8]);
        kr1 = *reinterpret_cast<const ushortx8*>(&kp[baseQ + (size_t)(sr + 32) * D + sc8]);
        vr0 = *reinterpret_cast<const ushortx8*>(&vt[baseV + (size_t)sr * S + sc8]);
        vr1 = *reinterpret_cast<const ushortx8*>(&vt[baseV + (size_t)(sr + 32) * S + sc8]);
    }

    for (int t = 0; t < NT - 1; ++t) {
        // write current tile to LDS
        *reinterpret_cast<ushortx8*>(&Ks[sr][sc8])       = kr0;
        *reinterpret_cast<ushortx8*>(&Ks[sr + 32][sc8])  = kr1;
        *reinterpret_cast<ushortx8*>(&Vts[sr][sc8])      = vr0;
        *reinterpret_cast<ushortx8*>(&Vts[sr + 32][sc8]) = vr1;
        __syncthreads();
        // issue next tile loads early (T14): latency hides under compute
        const int kt1 = (t + 1) * 64;
        const ushortx8 nk0 = *reinterpret_cast<const ushortx8*>(&kp[baseQ + (size_t)(kt1 + sr) * D + sc8]);
        const ushortx8 nk1 = *reinterpret_cast<const ushortx8*>(&kp[baseQ + (size_t)(kt1 + sr + 32) * D + sc8]);
        const ushortx8 nv0 = *reinterpret_cast<const ushortx8*>(&vt[baseV + (size_t)sr * S + kt1 + sc8]);
        const ushortx8 nv1 = *reinterpret_cast<const ushortx8*>(&vt[baseV + (size_t)(sr + 32) * S + kt1 + sc8]);
        if (t == NT - 2)
            attn_tile2<0>(Ks, Vts, Pls[w], qA0, qA1, qB0, qB1, oA, oB, lsA, lsB, w, fr, kg);
        else
            attn_tile2<-1>(Ks, Vts, Pls[w], qA0, qA1, qB0, qB1, oA, oB, lsA, lsB, w, fr, kg);
        __syncthreads();
        kr0 = nk0; kr1 = nk1; vr0 = nv0; vr1 = nv1;
    }
    // last (diagonal) tile
    *reinterpret_cast<ushortx8*>(&Ks[sr][sc8])       = kr0;
    *reinterpret_cast<ushortx8*>(&Ks[sr + 32][sc8])  = kr1;
    *reinterpret_cast<ushortx8*>(&Vts[sr][sc8])      = vr0;
    *reinterpret_cast<ushortx8*>(&Vts[sr + 32][sc8]) = vr1;
    __syncthreads();
    attn_tile2<1>(Ks, Vts, Pls[w], qA0, qA1, qB0, qB1, oA, oB, lsA, lsB, w, fr, kg);

    // full row sums: combine the 4 key-groups, add analytic tail count
    lsA += __shfl_xor(lsA, 16, 64);
    lsA += __shfl_xor(lsA, 32, 64);
    lsB += __shfl_xor(lsB, 16, 64);
    lsB += __shfl_xor(lsB, 32, 64);
    const float tailc = (float)(S - (qt + 1) * 128);
    lsA += tailc;
    lsB += tailc;

    float lqA[4], lqB[4];
    #pragma unroll
    for (int r = 0; r < 4; ++r) {
        lqA[r] = __shfl(lsA, kg * 4 + r, 64);
        lqB[r] = __shfl(lsB, kg * 4 + r, 64);
    }

    float tl[4];
    #pragma unroll
    for (int n = 0; n < 4; ++n)
        tl[n] = vtail[((size_t)(b * 1024) + h * 64 + n * 16 + fr) * 32 + 2 * qt + 1];

    #pragma unroll
    for (int n = 0; n < 4; ++n)
        #pragma unroll
        for (int r = 0; r < 4; ++r) {
            const int qa = qw0 + kg * 4 + r;
            ctx[baseQ + (size_t)qa * D + n * 16 + fr] = f2bf((oA[n][r] + tl[n]) / lqA[r]);
            ctx[baseQ + (size_t)(qa + 16) * D + n * 16 + fr] = f2bf((oB[n][r] + tl[n]) / lqB[r]);
        }
}

// ---------------------------------------------------------------------------
extern "C" void kernel_launch(void* const* d_in, const int* in_sizes, int n_in,
                              void* d_out, int out_size, void* d_ws, size_t ws_size,
                              hipStream_t stream) {
    constexpr int B = 2, S = 2048, D = 1024;
    constexpr int M = B * S;                 // 4096
    constexpr size_t MD = (size_t)M * D;     // 4M elements

    const float* Q  = (const float*)d_in[0];
    const float* K  = (const float*)d_in[1];
    const float* V  = (const float*)d_in[2];
    const float* Wq = (const float*)d_in[4];
    const float* bq = (const float*)d_in[5];
    const float* Wk = (const float*)d_in[6];
    const float* bk = (const float*)d_in[7];
    const float* Wv = (const float*)d_in[8];
    const float* bv = (const float*)d_in[9];
    const float* Wo = (const float*)d_in[10];
    const float* bo = (const float*)d_in[11];

    // d_out (16 MiB, dead until final GEMM): qc (8 MiB) + kc (8 MiB)
    unsigned short* qc = (unsigned short*)d_out;
    unsigned short* kc = qc + MD;
    // d_ws (40 MiB): qb, kb, vtg, vc/ctx (8 MiB each) + Wto/Wtq/Wtk/Wtv (2 MiB each)
    char* ws = (char*)d_ws;
    unsigned short* qb  = (unsigned short*)(ws);
    unsigned short* kb  = (unsigned short*)(ws + (8u << 20));
    unsigned short* vtg = (unsigned short*)(ws + (16u << 20));
    unsigned short* vc  = (unsigned short*)(ws + (24u << 20));
    unsigned short* Wto = (unsigned short*)(ws + (32u << 20));
    unsigned short* Wtq = (unsigned short*)(ws + (34u << 20));
    unsigned short* Wtk = (unsigned short*)(ws + (36u << 20));
    unsigned short* Wtv = (unsigned short*)(ws + (38u << 20));
    unsigned short* ctx = vc;                       // aliases vc (dead by then)
    float* vtail        = (float*)Wtq;              // aliases Wtq (dead by then)

    dim3 blk(256);
    k_cvt<<<dim3(1024, 3), blk, 0, stream>>>(Q, K, V, qc, kc, vc);
    k_wt<<<dim3(16, 16, 4), blk, 0, stream>>>(Wq, Wk, Wv, Wo, Wtq, Wtk, Wtv, Wto);
    k_gemm_bf16<1><<<dim3(M / 128, D / 128, 3), blk, 0, stream>>>(
        qc, kc, vc, Wtq, Wtk, Wtv, bq, bk, bv, qb, kb, vtg);
    k_vtail<<<dim3((B * D) / 4), blk, 0, stream>>>(vtg, vtail);
    k_attn<<<dim3(S / 128, 16, B), blk, 0, stream>>>(qb, kb, vtg, vtail, ctx);
    k_gemm_bf16<0><<<dim3(M / 128, D / 128, 1), blk, 0, stream>>>(
        ctx, ctx, ctx, Wto, Wto, Wto, bo, bo, bo, d_out, d_out, d_out);
}

// Round 7
// 146.327 us; speedup vs baseline: 1.0912x; 1.0912x over previous
//
#include <hip/hip_runtime.h>
#include <hip/hip_bf16.h>
#include <stdint.h>

#define DI __device__ __forceinline__

typedef __bf16 bf16x8 __attribute__((ext_vector_type(8)));
typedef float f32x4 __attribute__((ext_vector_type(4)));
typedef unsigned short ushortx8 __attribute__((ext_vector_type(8)));

// fp32 -> bf16 round-to-nearest-even (scalar path)
DI unsigned short f2bf(float f) {
    unsigned int u = __builtin_bit_cast(unsigned int, f);
    u += 0x7fffu + ((u >> 16) & 1u);
    return (unsigned short)(u >> 16);
}

// packed fp32x2 -> bf16x2 (1 VALU op). lo -> bits 0-15, hi -> bits 16-31.
DI unsigned int cvt_pk_bf16(float lo, float hi) {
    unsigned int r;
    asm("v_cvt_pk_bf16_f32 %0, %1, %2" : "=v"(r) : "v"(lo), "v"(hi));
    return r;
}

DI f32x4 mfma_16x16x32_bf16(bf16x8 a, bf16x8 b, f32x4 c) {
    return __builtin_amdgcn_mfma_f32_16x16x32_bf16(a, b, c, 0, 0, 0);
}

// async global->LDS, 16B per lane. LDS dest: wave-uniform base + lane*16.
DI void gload16(const unsigned short* g, unsigned short* l) {
    __builtin_amdgcn_global_load_lds(
        (const __attribute__((address_space(1))) void*)g,
        (__attribute__((address_space(3))) void*)l, 16, 0, 0);
}

// ---------------------------------------------------------------------------
// k_cvt: fp32 -> bf16 elementwise for Q, K, V (grid.y selects tensor).
// ---------------------------------------------------------------------------
__global__ __launch_bounds__(256) void k_cvt(
    const float* __restrict__ s0, const float* __restrict__ s1, const float* __restrict__ s2,
    unsigned short* __restrict__ d0, unsigned short* __restrict__ d1, unsigned short* __restrict__ d2)
{
    const int z = blockIdx.y;
    const float* s = z == 0 ? s0 : z == 1 ? s1 : s2;
    unsigned short* d = z == 0 ? d0 : z == 1 ? d1 : d2;
    const int i0 = blockIdx.x * 256 + threadIdx.x;
    #pragma unroll
    for (int it = 0; it < 4; ++it) {
        const int i = i0 + it * 262144;
        const float4 v = reinterpret_cast<const float4*>(s)[i];
        uint2 pk;
        pk.x = cvt_pk_bf16(v.x, v.y);
        pk.y = cvt_pk_bf16(v.z, v.w);
        reinterpret_cast<uint2*>(d)[i] = pk;
    }
}

// ---------------------------------------------------------------------------
// k_wt: W fp32 [1024][1024] -> Wt bf16 [n][k] (transposed), grid.z = 4 matrices.
// ---------------------------------------------------------------------------
__global__ __launch_bounds__(256) void k_wt(
    const float* __restrict__ w0, const float* __restrict__ w1,
    const float* __restrict__ w2, const float* __restrict__ w3,
    unsigned short* __restrict__ o0, unsigned short* __restrict__ o1,
    unsigned short* __restrict__ o2, unsigned short* __restrict__ o3)
{
    constexpr int N = 1024;
    const int z = blockIdx.z;
    const float* W = z == 0 ? w0 : z == 1 ? w1 : z == 2 ? w2 : w3;
    unsigned short* O = z == 0 ? o0 : z == 1 ? o1 : z == 2 ? o2 : o3;

    __shared__ unsigned short L[64 * 64];
    const int tid = threadIdx.x;
    const int k0 = blockIdx.x * 64, n0 = blockIdx.y * 64;

    const int r = tid >> 2, cbase = (tid & 3) * 16;
    #pragma unroll
    for (int i = 0; i < 4; ++i) {
        const int c = cbase + i * 4;
        const float4 v = *reinterpret_cast<const float4*>(&W[(size_t)(k0 + r) * N + n0 + c]);
        uint2 pk;
        pk.x = cvt_pk_bf16(v.x, v.y);
        pk.y = cvt_pk_bf16(v.z, v.w);
        const int byte = r * 128 + ((c * 2) ^ ((r & 7) << 4));
        *reinterpret_cast<uint2*>(reinterpret_cast<char*>(L) + byte) = pk;
    }
    __syncthreads();

    const int n = tid >> 2, kc = (tid & 3) * 16;
    ushortx8 v0, v1;
    #pragma unroll
    for (int j = 0; j < 8; ++j) {
        const int ka = kc + j, kb2 = kc + 8 + j;
        v0[j] = *reinterpret_cast<const unsigned short*>(
            reinterpret_cast<const char*>(L) + ka * 128 + ((n * 2) ^ ((ka & 7) << 4)));
        v1[j] = *reinterpret_cast<const unsigned short*>(
            reinterpret_cast<const char*>(L) + kb2 * 128 + ((n * 2) ^ ((kb2 & 7) << 4)));
    }
    unsigned short* op = &O[(size_t)(n0 + n) * N + k0 + kc];
    *reinterpret_cast<ushortx8*>(op) = v0;
    *reinterpret_cast<ushortx8*>(op + 8) = v1;
}

// ---------------------------------------------------------------------------
// m97-style bf16 GEMM (unchanged).
// ---------------------------------------------------------------------------
template <int MODE>
__global__ __launch_bounds__(256) void k_gemm_bf16(
    const unsigned short* __restrict__ A0, const unsigned short* __restrict__ A1,
    const unsigned short* __restrict__ A2,
    const unsigned short* __restrict__ B0, const unsigned short* __restrict__ B1,
    const unsigned short* __restrict__ B2,
    const float* __restrict__ bias0, const float* __restrict__ bias1,
    const float* __restrict__ bias2,
    void* C0, void* C1, void* C2)
{
    constexpr int K = 1024, N = 1024;
    const int z = MODE ? blockIdx.z : 0;
    const unsigned short* A  = z == 0 ? A0 : z == 1 ? A1 : A2;
    const unsigned short* Bt = z == 0 ? B0 : z == 1 ? B1 : B2;
    const float* bias        = z == 0 ? bias0 : z == 1 ? bias1 : bias2;
    void* C                  = z == 0 ? C0 : z == 1 ? C1 : C2;

    __shared__ unsigned short As[128 * 32];
    __shared__ unsigned short Bs[128 * 32];

    const int tid  = threadIdx.x;
    const int lane = tid & 63;
    const int w    = tid >> 6;
    const int wr   = w >> 1, wc = w & 1;
    const int fr   = lane & 15, kg = lane >> 4;
    const int m0   = blockIdx.x * 128, n0 = blockIdx.y * 128;

    const int srow = lane >> 2;
    const int sk8  = (lane & 3) * 8;

    f32x4 acc[4][4] = {};

    for (int t = 0; t < K / 32; ++t) {
        const int k0 = t * 32;
        #pragma unroll
        for (int i = 0; i < 2; ++i) {
            const int c = w * 2 + i;
            const int row = c * 16 + srow;
            gload16(&A[(size_t)(m0 + row) * K + k0 + sk8], &As[c * 512]);
            gload16(&Bt[(size_t)(n0 + row) * K + k0 + sk8], &Bs[c * 512]);
        }
        __syncthreads();

        bf16x8 af[4], bfj[4];
        #pragma unroll
        for (int i = 0; i < 4; ++i)
            af[i] = *reinterpret_cast<const bf16x8*>(&As[(wr * 64 + i * 16 + fr) * 32 + kg * 8]);
        #pragma unroll
        for (int j = 0; j < 4; ++j)
            bfj[j] = *reinterpret_cast<const bf16x8*>(&Bs[(wc * 64 + j * 16 + fr) * 32 + kg * 8]);
        #pragma unroll
        for (int i = 0; i < 4; ++i)
            #pragma unroll
            for (int j = 0; j < 4; ++j)
                acc[i][j] = mfma_16x16x32_bf16(af[i], bfj[j], acc[i][j]);
        __syncthreads();
    }

    if (MODE == 1 && z == 2) {
        unsigned short* vt = reinterpret_cast<unsigned short*>(C);
        #pragma unroll
        for (int i = 0; i < 4; ++i) {
            const int m = m0 + wr * 64 + i * 16 + kg * 4;
            const int bb = m >> 11, s = m & 2047;
            #pragma unroll
            for (int j = 0; j < 4; ++j) {
                const int n = n0 + wc * 64 + j * 16 + fr;
                const float bv = bias[n];
                uint2 pk;
                pk.x = cvt_pk_bf16(acc[i][j][0] + bv, acc[i][j][1] + bv);
                pk.y = cvt_pk_bf16(acc[i][j][2] + bv, acc[i][j][3] + bv);
                *reinterpret_cast<uint2*>(&vt[((size_t)(bb * 1024 + n)) * 2048 + s]) = pk;
            }
        }
    } else if (MODE == 1) {
        const float sc = (z == 0) ? 0.125f : 1.0f;
        unsigned short* Cb = reinterpret_cast<unsigned short*>(C);
        #pragma unroll
        for (int i = 0; i < 4; ++i) {
            const int m = m0 + wr * 64 + i * 16 + kg * 4;
            #pragma unroll
            for (int j = 0; j < 4; ++j) {
                const int n = n0 + wc * 64 + j * 16 + fr;
                const float bv = bias[n];
                const unsigned int p0 = cvt_pk_bf16((acc[i][j][0] + bv) * sc, (acc[i][j][1] + bv) * sc);
                const unsigned int p1 = cvt_pk_bf16((acc[i][j][2] + bv) * sc, (acc[i][j][3] + bv) * sc);
                Cb[(size_t)(m + 0) * N + n] = (unsigned short)p0;
                Cb[(size_t)(m + 1) * N + n] = (unsigned short)(p0 >> 16);
                Cb[(size_t)(m + 2) * N + n] = (unsigned short)p1;
                Cb[(size_t)(m + 3) * N + n] = (unsigned short)(p1 >> 16);
            }
        }
    } else {
        float* Cf = reinterpret_cast<float*>(C);
        #pragma unroll
        for (int i = 0; i < 4; ++i) {
            const int m = m0 + wr * 64 + i * 16 + kg * 4;
            #pragma unroll
            for (int j = 0; j < 4; ++j) {
                const int n = n0 + wc * 64 + j * 16 + fr;
                const float bv = bias[n];
                #pragma unroll
                for (int r = 0; r < 4; ++r)
                    Cf[(size_t)(m + r) * N + n] = acc[i][j][r] + bv;
            }
        }
    }
}

// ---------------------------------------------------------------------------
// V tail suffix sums (unchanged).
// ---------------------------------------------------------------------------
__global__ __launch_bounds__(256) void k_vtail(
    const unsigned short* __restrict__ vt, float* __restrict__ vtail)
{
    const int row = blockIdx.x * 4 + (threadIdx.x >> 6);
    const int l = threadIdx.x & 63;
    const unsigned short* p = &vt[(size_t)row * 2048 + l * 32];
    float s = 0.f;
    #pragma unroll
    for (int i = 0; i < 4; ++i) {
        ushortx8 v = *reinterpret_cast<const ushortx8*>(&p[i * 8]);
        #pragma unroll
        for (int e = 0; e < 8; ++e)
            s += __builtin_bit_cast(float, (unsigned int)v[e] << 16);
    }
    #pragma unroll
    for (int off = 1; off < 64; off <<= 1) {
        const float t = __shfl_down(s, off, 64);
        s += (l + off < 64) ? t : 0.f;
    }
    float tv = __shfl(s, (2 * l + 2) & 63, 64);
    if (l == 31) tv = 0.f;
    if (l < 32) vtail[(size_t)row * 32 + l] = tv;
}

// ---------------------------------------------------------------------------
// Attention v5: QBLK=64 (grid 1024 blocks -> 4/CU), fully XOR-swizzled LDS
// (K, V, P at [64][128B] stride, byte ^= (row&7)<<4, no padding -> 24 KB),
// T14 register prefetch of next K/V tile, biggest-first qt order.
// Swapped QK^T + causal tile skip + V-tail substitution as before.
// ---------------------------------------------------------------------------
template <bool MASK>
DI void attn_tile(const unsigned char* KsB, const unsigned char* VtsB,
                  unsigned char* PB, bf16x8 qf0, bf16x8 qf1,
                  f32x4 (&o)[4], float& lsum, int w, int fr, int kg)
{
    const int sw = (fr & 7) << 4;
    #pragma unroll
    for (int j = 0; j < 4; ++j) {
        const int row = j * 16 + fr;
        const bf16x8 kf0 = *reinterpret_cast<const bf16x8*>(KsB + row * 128 + ((kg * 16) ^ sw));
        const bf16x8 kf1 = *reinterpret_cast<const bf16x8*>(KsB + row * 128 + ((64 + kg * 16) ^ sw));
        f32x4 s = {0.f, 0.f, 0.f, 0.f};
        s = mfma_16x16x32_bf16(kf0, qf0, s);   // swapped: A=K rows (keys), B=Q
        s = mfma_16x16x32_bf16(kf1, qf1, s);
        float p[4];
        #pragma unroll
        for (int r = 0; r < 4; ++r) {
            float e = __expf(s[r]);
            if (MASK && (j * 16 + kg * 4 + r > w * 16 + fr)) e = 1.0f;  // exp(-1e-8)==1.0f
            p[r] = e;
            lsum += e;
        }
        uint2 pk;
        pk.x = cvt_pk_bf16(p[0], p[1]);
        pk.y = cvt_pk_bf16(p[2], p[3]);
        *reinterpret_cast<uint2*>(PB + fr * 128 + ((j * 32 + kg * 8) ^ sw)) = pk;
    }
    #pragma unroll
    for (int kk = 0; kk < 2; ++kk) {
        const bf16x8 pf = *reinterpret_cast<const bf16x8*>(PB + fr * 128 + ((kk * 64 + kg * 16) ^ sw));
        #pragma unroll
        for (int n = 0; n < 4; ++n) {
            const int vrow = n * 16 + fr;
            const bf16x8 vf = *reinterpret_cast<const bf16x8*>(VtsB + vrow * 128 + ((kk * 64 + kg * 16) ^ sw));
            o[n] = mfma_16x16x32_bf16(pf, vf, o[n]);
        }
    }
}

__global__ __launch_bounds__(256, 4) void k_attn(
    const unsigned short* __restrict__ qp,
    const unsigned short* __restrict__ kp,
    const unsigned short* __restrict__ vt,
    const float* __restrict__ vtail,
    unsigned short* __restrict__ ctx)
{
    constexpr int S = 2048, D = 1024;
    const int qt = (S / 64 - 1) - blockIdx.x;    // biggest-first dispatch
    const int h  = blockIdx.y;
    const int b  = blockIdx.z;

    __shared__ alignas(16) unsigned char KsB[64 * 128];    // [key][d]   swizzled
    __shared__ alignas(16) unsigned char VtsB[64 * 128];   // [d][key]   swizzled
    __shared__ alignas(16) unsigned char PlsB[4 * 16 * 128]; // per-wave P swizzled

    const int tid  = threadIdx.x;
    const int lane = tid & 63, w = tid >> 6;
    const int fr   = lane & 15, kg = lane >> 4;
    unsigned char* PB = PlsB + w * 2048;

    const size_t baseQ = ((size_t)b * S) * D + (size_t)h * 64;
    const size_t baseV = ((size_t)b * D + (size_t)h * 64) * S;
    const int q0 = qt * 64 + w * 16;

    bf16x8 qf0, qf1;
    {
        const size_t roff = baseQ + (size_t)(q0 + fr) * D;
        qf0 = *reinterpret_cast<const bf16x8*>(&qp[roff + kg * 8]);
        qf1 = *reinterpret_cast<const bf16x8*>(&qp[roff + 32 + kg * 8]);
    }

    f32x4 o[4] = {};
    float lsum = 0.f;

    // staging: thread covers rows sr and sr+32 of both K and V tiles
    const int sr  = tid >> 3;          // 0..31
    const int sc  = tid & 7;           // 16B column 0..7
    const int sc8 = sc * 8;            // element offset (8 bf16)
    const int wb0 = sr * 128 + ((sc * 16) ^ ((sr & 7) << 4));
    const int wb1 = (sr + 32) * 128 + ((sc * 16) ^ (((sr + 32) & 7) << 4));
    const int NT  = qt + 1;            // tiles to sweep (last is diagonal)

    // prologue: load tile 0 into registers
    ushortx8 kr0 = *reinterpret_cast<const ushortx8*>(&kp[baseQ + (size_t)sr * D + sc8]);
    ushortx8 kr1 = *reinterpret_cast<const ushortx8*>(&kp[baseQ + (size_t)(sr + 32) * D + sc8]);
    ushortx8 vr0 = *reinterpret_cast<const ushortx8*>(&vt[baseV + (size_t)sr * S + sc8]);
    ushortx8 vr1 = *reinterpret_cast<const ushortx8*>(&vt[baseV + (size_t)(sr + 32) * S + sc8]);

    for (int t = 0; t < NT - 1; ++t) {
        // write current tile to LDS (swizzled)
        *reinterpret_cast<ushortx8*>(KsB + wb0)  = kr0;
        *reinterpret_cast<ushortx8*>(KsB + wb1)  = kr1;
        *reinterpret_cast<ushortx8*>(VtsB + wb0) = vr0;
        *reinterpret_cast<ushortx8*>(VtsB + wb1) = vr1;
        __syncthreads();
        // T14: issue next tile loads early; latency hides under compute
        const int kt1 = (t + 1) * 64;
        const ushortx8 nk0 = *reinterpret_cast<const ushortx8*>(&kp[baseQ + (size_t)(kt1 + sr) * D + sc8]);
        const ushortx8 nk1 = *reinterpret_cast<const ushortx8*>(&kp[baseQ + (size_t)(kt1 + sr + 32) * D + sc8]);
        const ushortx8 nv0 = *reinterpret_cast<const ushortx8*>(&vt[baseV + (size_t)sr * S + kt1 + sc8]);
        const ushortx8 nv1 = *reinterpret_cast<const ushortx8*>(&vt[baseV + (size_t)(sr + 32) * S + kt1 + sc8]);
        attn_tile<false>(KsB, VtsB, PB, qf0, qf1, o, lsum, w, fr, kg);
        __syncthreads();
        kr0 = nk0; kr1 = nk1; vr0 = nv0; vr1 = nv1;
    }
    // last (diagonal) tile
    *reinterpret_cast<ushortx8*>(KsB + wb0)  = kr0;
    *reinterpret_cast<ushortx8*>(KsB + wb1)  = kr1;
    *reinterpret_cast<ushortx8*>(VtsB + wb0) = vr0;
    *reinterpret_cast<ushortx8*>(VtsB + wb1) = vr1;
    __syncthreads();
    attn_tile<true>(KsB, VtsB, PB, qf0, qf1, o, lsum, w, fr, kg);

    // full row sums: combine the 4 key-groups, add analytic tail count
    lsum += __shfl_xor(lsum, 16, 64);
    lsum += __shfl_xor(lsum, 32, 64);
    lsum += (float)(S - (qt + 1) * 64);

    float lq[4];
    #pragma unroll
    for (int r = 0; r < 4; ++r) lq[r] = __shfl(lsum, kg * 4 + r, 64);

    float tl[4];
    #pragma unroll
    for (int n = 0; n < 4; ++n)
        tl[n] = vtail[((size_t)(b * 1024) + h * 64 + n * 16 + fr) * 32 + qt];

    #pragma unroll
    for (int n = 0; n < 4; ++n)
        #pragma unroll
        for (int r = 0; r < 4; ++r) {
            const int qrow = q0 + kg * 4 + r;
            ctx[baseQ + (size_t)qrow * D + n * 16 + fr] = f2bf((o[n][r] + tl[n]) / lq[r]);
        }
}

// ---------------------------------------------------------------------------
extern "C" void kernel_launch(void* const* d_in, const int* in_sizes, int n_in,
                              void* d_out, int out_size, void* d_ws, size_t ws_size,
                              hipStream_t stream) {
    constexpr int B = 2, S = 2048, D = 1024;
    constexpr int M = B * S;                 // 4096
    constexpr size_t MD = (size_t)M * D;     // 4M elements

    const float* Q  = (const float*)d_in[0];
    const float* K  = (const float*)d_in[1];
    const float* V  = (const float*)d_in[2];
    const float* Wq = (const float*)d_in[4];
    const float* bq = (const float*)d_in[5];
    const float* Wk = (const float*)d_in[6];
    const float* bk = (const float*)d_in[7];
    const float* Wv = (const float*)d_in[8];
    const float* bv = (const float*)d_in[9];
    const float* Wo = (const float*)d_in[10];
    const float* bo = (const float*)d_in[11];

    // d_out (16 MiB, dead until final GEMM): qc (8 MiB) + kc (8 MiB)
    unsigned short* qc = (unsigned short*)d_out;
    unsigned short* kc = qc + MD;
    // d_ws (40 MiB): qb, kb, vtg, vc/ctx (8 MiB each) + Wto/Wtq/Wtk/Wtv (2 MiB each)
    char* ws = (char*)d_ws;
    unsigned short* qb  = (unsigned short*)(ws);
    unsigned short* kb  = (unsigned short*)(ws + (8u << 20));
    unsigned short* vtg = (unsigned short*)(ws + (16u << 20));
    unsigned short* vc  = (unsigned short*)(ws + (24u << 20));
    unsigned short* Wto = (unsigned short*)(ws + (32u << 20));
    unsigned short* Wtq = (unsigned short*)(ws + (34u << 20));
    unsigned short* Wtk = (unsigned short*)(ws + (36u << 20));
    unsigned short* Wtv = (unsigned short*)(ws + (38u << 20));
    unsigned short* ctx = vc;                       // aliases vc (dead by then)
    float* vtail        = (float*)Wtq;              // aliases Wtq (dead by then)

    dim3 blk(256);
    k_cvt<<<dim3(1024, 3), blk, 0, stream>>>(Q, K, V, qc, kc, vc);
    k_wt<<<dim3(16, 16, 4), blk, 0, stream>>>(Wq, Wk, Wv, Wo, Wtq, Wtk, Wtv, Wto);
    k_gemm_bf16<1><<<dim3(M / 128, D / 128, 3), blk, 0, stream>>>(
        qc, kc, vc, Wtq, Wtk, Wtv, bq, bk, bv, qb, kb, vtg);
    k_vtail<<<dim3((B * D) / 4), blk, 0, stream>>>(vtg, vtail);
    k_attn<<<dim3(S / 64, 16, B), blk, 0, stream>>>(qb, kb, vtg, vtail, ctx);
    k_gemm_bf16<0><<<dim3(M / 128, D / 128, 1), blk, 0, stream>>>(
        ctx, ctx, ctx, Wto, Wto, Wto, bo, bo, bo, d_out, d_out, d_out);
}

// Round 8
// 139.572 us; speedup vs baseline: 1.1440x; 1.0484x over previous
//
#include <hip/hip_runtime.h>
#include <hip/hip_bf16.h>
#include <stdint.h>

#define DI __device__ __forceinline__

typedef __bf16 bf16x8 __attribute__((ext_vector_type(8)));
typedef float f32x4 __attribute__((ext_vector_type(4)));
typedef unsigned short ushortx8 __attribute__((ext_vector_type(8)));

// fp32 -> bf16 round-to-nearest-even (scalar path)
DI unsigned short f2bf(float f) {
    unsigned int u = __builtin_bit_cast(unsigned int, f);
    u += 0x7fffu + ((u >> 16) & 1u);
    return (unsigned short)(u >> 16);
}

// packed fp32x2 -> bf16x2 (1 VALU op). lo -> bits 0-15, hi -> bits 16-31.
DI unsigned int cvt_pk_bf16(float lo, float hi) {
    unsigned int r;
    asm("v_cvt_pk_bf16_f32 %0, %1, %2" : "=v"(r) : "v"(lo), "v"(hi));
    return r;
}

DI f32x4 mfma_16x16x32_bf16(bf16x8 a, bf16x8 b, f32x4 c) {
    return __builtin_amdgcn_mfma_f32_16x16x32_bf16(a, b, c, 0, 0, 0);
}

// async global->LDS, 16B per lane. LDS dest: wave-uniform base + lane*16.
DI void gload16(const unsigned short* g, unsigned short* l) {
    __builtin_amdgcn_global_load_lds(
        (const __attribute__((address_space(1))) void*)g,
        (__attribute__((address_space(3))) void*)l, 16, 0, 0);
}

// ---------------------------------------------------------------------------
// k_cvt: fp32 -> bf16 elementwise for Q, K, V (grid.y selects tensor).
// ---------------------------------------------------------------------------
__global__ __launch_bounds__(256) void k_cvt(
    const float* __restrict__ s0, const float* __restrict__ s1, const float* __restrict__ s2,
    unsigned short* __restrict__ d0, unsigned short* __restrict__ d1, unsigned short* __restrict__ d2)
{
    const int z = blockIdx.y;
    const float* s = z == 0 ? s0 : z == 1 ? s1 : s2;
    unsigned short* d = z == 0 ? d0 : z == 1 ? d1 : d2;
    const int i0 = blockIdx.x * 256 + threadIdx.x;
    #pragma unroll
    for (int it = 0; it < 4; ++it) {
        const int i = i0 + it * 262144;
        const float4 v = reinterpret_cast<const float4*>(s)[i];
        uint2 pk;
        pk.x = cvt_pk_bf16(v.x, v.y);
        pk.y = cvt_pk_bf16(v.z, v.w);
        reinterpret_cast<uint2*>(d)[i] = pk;
    }
}

// ---------------------------------------------------------------------------
// k_wt: W fp32 [1024][1024] -> Wt bf16 [n][k] (transposed), grid.z = 4 matrices.
// ---------------------------------------------------------------------------
__global__ __launch_bounds__(256) void k_wt(
    const float* __restrict__ w0, const float* __restrict__ w1,
    const float* __restrict__ w2, const float* __restrict__ w3,
    unsigned short* __restrict__ o0, unsigned short* __restrict__ o1,
    unsigned short* __restrict__ o2, unsigned short* __restrict__ o3)
{
    constexpr int N = 1024;
    const int z = blockIdx.z;
    const float* W = z == 0 ? w0 : z == 1 ? w1 : z == 2 ? w2 : w3;
    unsigned short* O = z == 0 ? o0 : z == 1 ? o1 : z == 2 ? o2 : o3;

    __shared__ unsigned short L[64 * 64];
    const int tid = threadIdx.x;
    const int k0 = blockIdx.x * 64, n0 = blockIdx.y * 64;

    const int r = tid >> 2, cbase = (tid & 3) * 16;
    #pragma unroll
    for (int i = 0; i < 4; ++i) {
        const int c = cbase + i * 4;
        const float4 v = *reinterpret_cast<const float4*>(&W[(size_t)(k0 + r) * N + n0 + c]);
        uint2 pk;
        pk.x = cvt_pk_bf16(v.x, v.y);
        pk.y = cvt_pk_bf16(v.z, v.w);
        const int byte = r * 128 + ((c * 2) ^ ((r & 7) << 4));
        *reinterpret_cast<uint2*>(reinterpret_cast<char*>(L) + byte) = pk;
    }
    __syncthreads();

    const int n = tid >> 2, kc = (tid & 3) * 16;
    ushortx8 v0, v1;
    #pragma unroll
    for (int j = 0; j < 8; ++j) {
        const int ka = kc + j, kb2 = kc + 8 + j;
        v0[j] = *reinterpret_cast<const unsigned short*>(
            reinterpret_cast<const char*>(L) + ka * 128 + ((n * 2) ^ ((ka & 7) << 4)));
        v1[j] = *reinterpret_cast<const unsigned short*>(
            reinterpret_cast<const char*>(L) + kb2 * 128 + ((n * 2) ^ ((kb2 & 7) << 4)));
    }
    unsigned short* op = &O[(size_t)(n0 + n) * N + k0 + kc];
    *reinterpret_cast<ushortx8*>(op) = v0;
    *reinterpret_cast<ushortx8*>(op + 8) = v1;
}

// ---------------------------------------------------------------------------
// m97-style bf16 GEMM (unchanged).
// ---------------------------------------------------------------------------
template <int MODE>
__global__ __launch_bounds__(256) void k_gemm_bf16(
    const unsigned short* __restrict__ A0, const unsigned short* __restrict__ A1,
    const unsigned short* __restrict__ A2,
    const unsigned short* __restrict__ B0, const unsigned short* __restrict__ B1,
    const unsigned short* __restrict__ B2,
    const float* __restrict__ bias0, const float* __restrict__ bias1,
    const float* __restrict__ bias2,
    void* C0, void* C1, void* C2)
{
    constexpr int K = 1024, N = 1024;
    const int z = MODE ? blockIdx.z : 0;
    const unsigned short* A  = z == 0 ? A0 : z == 1 ? A1 : A2;
    const unsigned short* Bt = z == 0 ? B0 : z == 1 ? B1 : B2;
    const float* bias        = z == 0 ? bias0 : z == 1 ? bias1 : bias2;
    void* C                  = z == 0 ? C0 : z == 1 ? C1 : C2;

    __shared__ unsigned short As[128 * 32];
    __shared__ unsigned short Bs[128 * 32];

    const int tid  = threadIdx.x;
    const int lane = tid & 63;
    const int w    = tid >> 6;
    const int wr   = w >> 1, wc = w & 1;
    const int fr   = lane & 15, kg = lane >> 4;
    const int m0   = blockIdx.x * 128, n0 = blockIdx.y * 128;

    const int srow = lane >> 2;
    const int sk8  = (lane & 3) * 8;

    f32x4 acc[4][4] = {};

    for (int t = 0; t < K / 32; ++t) {
        const int k0 = t * 32;
        #pragma unroll
        for (int i = 0; i < 2; ++i) {
            const int c = w * 2 + i;
            const int row = c * 16 + srow;
            gload16(&A[(size_t)(m0 + row) * K + k0 + sk8], &As[c * 512]);
            gload16(&Bt[(size_t)(n0 + row) * K + k0 + sk8], &Bs[c * 512]);
        }
        __syncthreads();

        bf16x8 af[4], bfj[4];
        #pragma unroll
        for (int i = 0; i < 4; ++i)
            af[i] = *reinterpret_cast<const bf16x8*>(&As[(wr * 64 + i * 16 + fr) * 32 + kg * 8]);
        #pragma unroll
        for (int j = 0; j < 4; ++j)
            bfj[j] = *reinterpret_cast<const bf16x8*>(&Bs[(wc * 64 + j * 16 + fr) * 32 + kg * 8]);
        #pragma unroll
        for (int i = 0; i < 4; ++i)
            #pragma unroll
            for (int j = 0; j < 4; ++j)
                acc[i][j] = mfma_16x16x32_bf16(af[i], bfj[j], acc[i][j]);
        __syncthreads();
    }

    if (MODE == 1 && z == 2) {
        unsigned short* vt = reinterpret_cast<unsigned short*>(C);
        #pragma unroll
        for (int i = 0; i < 4; ++i) {
            const int m = m0 + wr * 64 + i * 16 + kg * 4;
            const int bb = m >> 11, s = m & 2047;
            #pragma unroll
            for (int j = 0; j < 4; ++j) {
                const int n = n0 + wc * 64 + j * 16 + fr;
                const float bv = bias[n];
                uint2 pk;
                pk.x = cvt_pk_bf16(acc[i][j][0] + bv, acc[i][j][1] + bv);
                pk.y = cvt_pk_bf16(acc[i][j][2] + bv, acc[i][j][3] + bv);
                *reinterpret_cast<uint2*>(&vt[((size_t)(bb * 1024 + n)) * 2048 + s]) = pk;
            }
        }
    } else if (MODE == 1) {
        const float sc = (z == 0) ? 0.125f : 1.0f;
        unsigned short* Cb = reinterpret_cast<unsigned short*>(C);
        #pragma unroll
        for (int i = 0; i < 4; ++i) {
            const int m = m0 + wr * 64 + i * 16 + kg * 4;
            #pragma unroll
            for (int j = 0; j < 4; ++j) {
                const int n = n0 + wc * 64 + j * 16 + fr;
                const float bv = bias[n];
                const unsigned int p0 = cvt_pk_bf16((acc[i][j][0] + bv) * sc, (acc[i][j][1] + bv) * sc);
                const unsigned int p1 = cvt_pk_bf16((acc[i][j][2] + bv) * sc, (acc[i][j][3] + bv) * sc);
                Cb[(size_t)(m + 0) * N + n] = (unsigned short)p0;
                Cb[(size_t)(m + 1) * N + n] = (unsigned short)(p0 >> 16);
                Cb[(size_t)(m + 2) * N + n] = (unsigned short)p1;
                Cb[(size_t)(m + 3) * N + n] = (unsigned short)(p1 >> 16);
            }
        }
    } else {
        float* Cf = reinterpret_cast<float*>(C);
        #pragma unroll
        for (int i = 0; i < 4; ++i) {
            const int m = m0 + wr * 64 + i * 16 + kg * 4;
            #pragma unroll
            for (int j = 0; j < 4; ++j) {
                const int n = n0 + wc * 64 + j * 16 + fr;
                const float bv = bias[n];
                #pragma unroll
                for (int r = 0; r < 4; ++r)
                    Cf[(size_t)(m + r) * N + n] = acc[i][j][r] + bv;
            }
        }
    }
}

// ---------------------------------------------------------------------------
// V tail suffix sums (unchanged).
// ---------------------------------------------------------------------------
__global__ __launch_bounds__(256) void k_vtail(
    const unsigned short* __restrict__ vt, float* __restrict__ vtail)
{
    const int row = blockIdx.x * 4 + (threadIdx.x >> 6);
    const int l = threadIdx.x & 63;
    const unsigned short* p = &vt[(size_t)row * 2048 + l * 32];
    float s = 0.f;
    #pragma unroll
    for (int i = 0; i < 4; ++i) {
        ushortx8 v = *reinterpret_cast<const ushortx8*>(&p[i * 8]);
        #pragma unroll
        for (int e = 0; e < 8; ++e)
            s += __builtin_bit_cast(float, (unsigned int)v[e] << 16);
    }
    #pragma unroll
    for (int off = 1; off < 64; off <<= 1) {
        const float t = __shfl_down(s, off, 64);
        s += (l + off < 64) ? t : 0.f;
    }
    float tv = __shfl(s, (2 * l + 2) & 63, 64);
    if (l == 31) tv = 0.f;
    if (l < 32) vtail[(size_t)row * 32 + l] = tv;
}

// ---------------------------------------------------------------------------
// Attention v6: causal PAIR balancing -- block p handles q-tiles (31-p) and p,
// always 33 key-tiles total -> 512 uniform blocks, exactly 2/CU, no tail.
// K/V LDS double-buffered (one barrier per tile); XOR-swizzled LDS; T14
// register prefetch. Swapped QK^T + V-tail substitution as before.
// ---------------------------------------------------------------------------
template <bool MASK>
DI void attn_tile(const unsigned char* KsB, const unsigned char* VtsB,
                  unsigned char* PB, bf16x8 qf0, bf16x8 qf1,
                  f32x4 (&o)[4], float& lsum, int w, int fr, int kg)
{
    const int sw = (fr & 7) << 4;
    #pragma unroll
    for (int j = 0; j < 4; ++j) {
        const int row = j * 16 + fr;
        const bf16x8 kf0 = *reinterpret_cast<const bf16x8*>(KsB + row * 128 + ((kg * 16) ^ sw));
        const bf16x8 kf1 = *reinterpret_cast<const bf16x8*>(KsB + row * 128 + ((64 + kg * 16) ^ sw));
        f32x4 s = {0.f, 0.f, 0.f, 0.f};
        s = mfma_16x16x32_bf16(kf0, qf0, s);   // swapped: A=K rows (keys), B=Q
        s = mfma_16x16x32_bf16(kf1, qf1, s);
        float p[4];
        #pragma unroll
        for (int r = 0; r < 4; ++r) {
            float e = __expf(s[r]);
            if (MASK && (j * 16 + kg * 4 + r > w * 16 + fr)) e = 1.0f;  // exp(-1e-8)==1.0f
            p[r] = e;
            lsum += e;
        }
        uint2 pk;
        pk.x = cvt_pk_bf16(p[0], p[1]);
        pk.y = cvt_pk_bf16(p[2], p[3]);
        *reinterpret_cast<uint2*>(PB + fr * 128 + ((j * 32 + kg * 8) ^ sw)) = pk;
    }
    #pragma unroll
    for (int kk = 0; kk < 2; ++kk) {
        const bf16x8 pf = *reinterpret_cast<const bf16x8*>(PB + fr * 128 + ((kk * 64 + kg * 16) ^ sw));
        #pragma unroll
        for (int n = 0; n < 4; ++n) {
            const int vrow = n * 16 + fr;
            const bf16x8 vf = *reinterpret_cast<const bf16x8*>(VtsB + vrow * 128 + ((kk * 64 + kg * 16) ^ sw));
            o[n] = mfma_16x16x32_bf16(pf, vf, o[n]);
        }
    }
}

DI void attn_sweep(int qt,
                   const unsigned short* __restrict__ qp,
                   const unsigned short* __restrict__ kp,
                   const unsigned short* __restrict__ vt,
                   const float* __restrict__ vtail,
                   unsigned short* __restrict__ ctx,
                   unsigned char (*KsB)[64 * 128], unsigned char (*VtsB)[64 * 128],
                   unsigned char* PB, size_t baseQ, size_t baseV, int b, int h,
                   int w, int fr, int kg, int sr, int sc8, int wb0, int wb1)
{
    constexpr int S = 2048, D = 1024;
    const int q0 = qt * 64 + w * 16;

    bf16x8 qf0, qf1;
    {
        const size_t roff = baseQ + (size_t)(q0 + fr) * D;
        qf0 = *reinterpret_cast<const bf16x8*>(&qp[roff + kg * 8]);
        qf1 = *reinterpret_cast<const bf16x8*>(&qp[roff + 32 + kg * 8]);
    }

    f32x4 o[4] = {};
    float lsum = 0.f;
    const int NT = qt + 1;

    // prologue: stage tile 0 into buffer 0
    {
        const ushortx8 kr0 = *reinterpret_cast<const ushortx8*>(&kp[baseQ + (size_t)sr * D + sc8]);
        const ushortx8 kr1 = *reinterpret_cast<const ushortx8*>(&kp[baseQ + (size_t)(sr + 32) * D + sc8]);
        const ushortx8 vr0 = *reinterpret_cast<const ushortx8*>(&vt[baseV + (size_t)sr * S + sc8]);
        const ushortx8 vr1 = *reinterpret_cast<const ushortx8*>(&vt[baseV + (size_t)(sr + 32) * S + sc8]);
        *reinterpret_cast<ushortx8*>(KsB[0] + wb0)  = kr0;
        *reinterpret_cast<ushortx8*>(KsB[0] + wb1)  = kr1;
        *reinterpret_cast<ushortx8*>(VtsB[0] + wb0) = vr0;
        *reinterpret_cast<ushortx8*>(VtsB[0] + wb1) = vr1;
    }
    __syncthreads();

    for (int t = 0; t < NT; ++t) {
        const int cur = t & 1;
        const bool more = (t + 1 < NT);
        ushortx8 nk0, nk1, nv0, nv1;
        if (more) {   // T14: issue next-tile loads before compute
            const int kt1 = (t + 1) * 64;
            nk0 = *reinterpret_cast<const ushortx8*>(&kp[baseQ + (size_t)(kt1 + sr) * D + sc8]);
            nk1 = *reinterpret_cast<const ushortx8*>(&kp[baseQ + (size_t)(kt1 + sr + 32) * D + sc8]);
            nv0 = *reinterpret_cast<const ushortx8*>(&vt[baseV + (size_t)sr * S + kt1 + sc8]);
            nv1 = *reinterpret_cast<const ushortx8*>(&vt[baseV + (size_t)(sr + 32) * S + kt1 + sc8]);
        }
        if (more)
            attn_tile<false>(KsB[cur], VtsB[cur], PB, qf0, qf1, o, lsum, w, fr, kg);
        else
            attn_tile<true>(KsB[cur], VtsB[cur], PB, qf0, qf1, o, lsum, w, fr, kg);
        if (more) {   // write next tile into the other buffer (no extra barrier)
            const int nxt = cur ^ 1;
            *reinterpret_cast<ushortx8*>(KsB[nxt] + wb0)  = nk0;
            *reinterpret_cast<ushortx8*>(KsB[nxt] + wb1)  = nk1;
            *reinterpret_cast<ushortx8*>(VtsB[nxt] + wb0) = nv0;
            *reinterpret_cast<ushortx8*>(VtsB[nxt] + wb1) = nv1;
        }
        __syncthreads();
    }

    // full row sums: combine the 4 key-groups, add analytic tail count
    lsum += __shfl_xor(lsum, 16, 64);
    lsum += __shfl_xor(lsum, 32, 64);
    lsum += (float)(S - (qt + 1) * 64);

    float lq[4];
    #pragma unroll
    for (int r = 0; r < 4; ++r) lq[r] = __shfl(lsum, kg * 4 + r, 64);

    float tl[4];
    #pragma unroll
    for (int n = 0; n < 4; ++n)
        tl[n] = vtail[((size_t)(b * 1024) + h * 64 + n * 16 + fr) * 32 + qt];

    #pragma unroll
    for (int n = 0; n < 4; ++n)
        #pragma unroll
        for (int r = 0; r < 4; ++r) {
            const int qrow = q0 + kg * 4 + r;
            ctx[baseQ + (size_t)qrow * D + n * 16 + fr] = f2bf((o[n][r] + tl[n]) / lq[r]);
        }
}

__global__ __launch_bounds__(256, 2) void k_attn(
    const unsigned short* __restrict__ qp,
    const unsigned short* __restrict__ kp,
    const unsigned short* __restrict__ vt,
    const float* __restrict__ vtail,
    unsigned short* __restrict__ ctx)
{
    constexpr int S = 2048, D = 1024;
    const int p = blockIdx.x;    // pair index 0..15
    const int h = blockIdx.y;
    const int b = blockIdx.z;

    __shared__ alignas(16) unsigned char KsB[2][64 * 128];     // dbuf K, swizzled
    __shared__ alignas(16) unsigned char VtsB[2][64 * 128];    // dbuf V, swizzled
    __shared__ alignas(16) unsigned char PlsB[4 * 16 * 128];   // per-wave P

    const int tid  = threadIdx.x;
    const int lane = tid & 63, w = tid >> 6;
    const int fr   = lane & 15, kg = lane >> 4;
    unsigned char* PB = PlsB + w * 2048;

    const size_t baseQ = ((size_t)b * S) * D + (size_t)h * 64;
    const size_t baseV = ((size_t)b * D + (size_t)h * 64) * S;

    const int sr  = tid >> 3;          // staging row 0..31
    const int sc8 = (tid & 7) * 8;     // element offset (8 bf16)
    const int wb0 = sr * 128 + (((tid & 7) * 16) ^ ((sr & 7) << 4));
    const int wb1 = (sr + 32) * 128 + (((tid & 7) * 16) ^ (((sr + 32) & 7) << 4));

    // pair (31-p, p): total key-tiles = (32-p) + (p+1) = 33, uniform
    attn_sweep(31 - p, qp, kp, vt, vtail, ctx, KsB, VtsB, PB,
               baseQ, baseV, b, h, w, fr, kg, sr, sc8, wb0, wb1);
    attn_sweep(p, qp, kp, vt, vtail, ctx, KsB, VtsB, PB,
               baseQ, baseV, b, h, w, fr, kg, sr, sc8, wb0, wb1);
}

// ---------------------------------------------------------------------------
extern "C" void kernel_launch(void* const* d_in, const int* in_sizes, int n_in,
                              void* d_out, int out_size, void* d_ws, size_t ws_size,
                              hipStream_t stream) {
    constexpr int B = 2, S = 2048, D = 1024;
    constexpr int M = B * S;                 // 4096
    constexpr size_t MD = (size_t)M * D;     // 4M elements

    const float* Q  = (const float*)d_in[0];
    const float* K  = (const float*)d_in[1];
    const float* V  = (const float*)d_in[2];
    const float* Wq = (const float*)d_in[4];
    const float* bq = (const float*)d_in[5];
    const float* Wk = (const float*)d_in[6];
    const float* bk = (const float*)d_in[7];
    const float* Wv = (const float*)d_in[8];
    const float* bv = (const float*)d_in[9];
    const float* Wo = (const float*)d_in[10];
    const float* bo = (const float*)d_in[11];

    // d_out (16 MiB, dead until final GEMM): qc (8 MiB) + kc (8 MiB)
    unsigned short* qc = (unsigned short*)d_out;
    unsigned short* kc = qc + MD;
    // d_ws (40 MiB): qb, kb, vtg, vc/ctx (8 MiB each) + Wto/Wtq/Wtk/Wtv (2 MiB each)
    char* ws = (char*)d_ws;
    unsigned short* qb  = (unsigned short*)(ws);
    unsigned short* kb  = (unsigned short*)(ws + (8u << 20));
    unsigned short* vtg = (unsigned short*)(ws + (16u << 20));
    unsigned short* vc  = (unsigned short*)(ws + (24u << 20));
    unsigned short* Wto = (unsigned short*)(ws + (32u << 20));
    unsigned short* Wtq = (unsigned short*)(ws + (34u << 20));
    unsigned short* Wtk = (unsigned short*)(ws + (36u << 20));
    unsigned short* Wtv = (unsigned short*)(ws + (38u << 20));
    unsigned short* ctx = vc;                       // aliases vc (dead by then)
    float* vtail        = (float*)Wtq;              // aliases Wtq (dead by then)

    dim3 blk(256);
    k_cvt<<<dim3(1024, 3), blk, 0, stream>>>(Q, K, V, qc, kc, vc);
    k_wt<<<dim3(16, 16, 4), blk, 0, stream>>>(Wq, Wk, Wv, Wo, Wtq, Wtk, Wtv, Wto);
    k_gemm_bf16<1><<<dim3(M / 128, D / 128, 3), blk, 0, stream>>>(
        qc, kc, vc, Wtq, Wtk, Wtv, bq, bk, bv, qb, kb, vtg);
    k_vtail<<<dim3((B * D) / 4), blk, 0, stream>>>(vtg, vtail);
    k_attn<<<dim3(16, 16, B), blk, 0, stream>>>(qb, kb, vtg, vtail, ctx);
    k_gemm_bf16<0><<<dim3(M / 128, D / 128, 1), blk, 0, stream>>>(
        ctx, ctx, ctx, Wto, Wto, Wto, bo, bo, bo, d_out, d_out, d_out);
}